// Round 1
// baseline (259.856 us; speedup 1.0000x reference)
//
#include <hip/hip_runtime.h>
#include <cstdint>
#include <cstddef>

typedef unsigned short u16;
typedef unsigned int   u32;
typedef __attribute__((ext_vector_type(8))) short short8;
typedef __attribute__((ext_vector_type(4))) float f32x4;
typedef __attribute__((ext_vector_type(4))) u16   u16x4;

// ---------- bf16 helpers (RNE) ----------
__device__ __forceinline__ float bf2f(u16 u){
  u32 x = ((u32)u) << 16; float f; __builtin_memcpy(&f, &x, 4); return f;
}
__device__ __forceinline__ u16 f2bf(float f){
  u32 x; __builtin_memcpy(&x, &f, 4);
  x += 0x7fffu + ((x >> 16) & 1u);
  return (u16)(x >> 16);
}

__device__ __forceinline__ void gload_lds16(const u16* g, u16* l){
  __builtin_amdgcn_global_load_lds((const __attribute__((address_space(1))) void*)g,
                                   (__attribute__((address_space(3))) void*)l, 16, 0, 0);
}

// ---------- fp32 -> bf16 convert (flat, 4 elems/thread) ----------
__global__ void convert_f2b(const float* __restrict__ src, u16* __restrict__ dst, int n4){
  int i = blockIdx.x * blockDim.x + threadIdx.x;
  if (i >= n4) return;
  float4 v = ((const float4*)src)[i];
  u16x4 o; o[0]=f2bf(v.x); o[1]=f2bf(v.y); o[2]=f2bf(v.z); o[3]=f2bf(v.w);
  ((u16x4*)dst)[i] = o;
}

// ---------- all small weight converts in one launch ----------
// segments (in float4 units): W1:16384, W2:8192, W3:8192, Wd1:8192, Wd2:16384, M1:16384, M2:16384
__global__ void convert_weights(const float* __restrict__ W1, const float* __restrict__ W2,
                                const float* __restrict__ W3, const float* __restrict__ Wd1,
                                const float* __restrict__ Wd2, const float* __restrict__ M1,
                                const float* __restrict__ M2,
                                u16* __restrict__ W1b, u16* __restrict__ Wcb,
                                u16* __restrict__ Wd1b, u16* __restrict__ Wd2b,
                                u16* __restrict__ M1b, u16* __restrict__ M2b){
  int j = blockIdx.x * blockDim.x + threadIdx.x;
  const float* src; u16* dst;
  if (j < 16384)              { src = W1;  dst = W1b; }
  else if ((j -= 16384) < 8192) { src = W2;  dst = Wcb; }
  else if ((j -= 8192)  < 8192) { src = W3;  dst = Wcb + 32768; }
  else if ((j -= 8192)  < 8192) { src = Wd1; dst = Wd1b; }
  else if ((j -= 8192)  < 16384){ src = Wd2; dst = Wd2b; }
  else if ((j -= 16384) < 16384){ src = M1;  dst = M1b; }
  else { j -= 16384; if (j >= 16384) return; src = M2; dst = M2b; }
  float4 v = ((const float4*)src)[j];
  u16x4 o; o[0]=f2bf(v.x); o[1]=f2bf(v.y); o[2]=f2bf(v.z); o[3]=f2bf(v.w);
  ((u16x4*)dst)[j] = o;
}

// ---------- gather-mean over 20 sampled neighbors ----------
// rows: bf16 [Nin][256] viewed as u32 [Nin][128]; 2 nodes per 256-thread block
__global__ void gather_mean(const u32* __restrict__ rows, const int* __restrict__ idx,
                            u32* __restrict__ out, int nout){
  const int node = blockIdx.x * 2 + (threadIdx.x >> 7);
  const int f = threadIdx.x & 127;
  if (node >= nout) return;
  const int* ip = idx + (size_t)node * 20;
  float a0 = 0.f, a1 = 0.f;
  #pragma unroll
  for (int s = 0; s < 20; ++s){
    const int j = ip[s];
    const u32 u = rows[(size_t)j * 128 + f];
    a0 += bf2f((u16)(u & 0xffffu));
    a1 += bf2f((u16)(u >> 16));
  }
  const float inv = 0.05f;
  out[(size_t)node * 128 + f] = (u32)f2bf(a0 * inv) | ((u32)f2bf(a1 * inv) << 16);
}

// ---------- reparameterize: h = eps*exp(logvar) + mu  (2 elems/thread, bf16 out) ----------
__global__ void reparam(const float* __restrict__ mu, const float* __restrict__ lv,
                        const float* __restrict__ eps, u32* __restrict__ h, int n2){
  int i = blockIdx.x * blockDim.x + threadIdx.x;
  if (i >= n2) return;
  float2 m = ((const float2*)mu)[i];
  float2 l = ((const float2*)lv)[i];
  float2 e = ((const float2*)eps)[i];
  float h0 = e.x * expf(l.x) + m.x;
  float h1 = e.y * expf(l.y) + m.y;
  h[i] = (u32)f2bf(h0) | ((u32)f2bf(h1) << 16);
}

// ---------- bf16 MFMA GEMM: C[M,N] = epi(A[M,K] @ B[N,K]^T) ----------
// 128x128 tile, BK=64, 4 waves (2x2 of 64x64), global_load_lds staging, double-buffered.
// EPI: 0=none 1=relu 2=tanh(x+bias) 3=x+bias
// OUT: 0=bf16 (ldc)  1=f32 (ldc)  2=f32 split cols 0-127->C[row*128+c], 128-255->C+M*128
template<int EPI, int OUT>
__global__ __launch_bounds__(256)
void gemm_bt(const u16* __restrict__ A, const u16* __restrict__ B,
             void* __restrict__ C, int ldc, const float* __restrict__ bias,
             int M, int N, int K)
{
  __shared__ u16 As[2][8192];
  __shared__ u16 Bs[2][8192];
  const int tid  = threadIdx.x;
  const int lane = tid & 63;
  const int wave = tid >> 6;
  const int wm = wave >> 1, wn = wave & 1;
  const int m0 = blockIdx.x * 128, n0 = blockIdx.y * 128;
  const int nkt = K >> 6;

  f32x4 acc[4][4];
  #pragma unroll
  for (int a = 0; a < 4; ++a)
    #pragma unroll
    for (int b = 0; b < 4; ++b)
      acc[a][b] = (f32x4){0.f, 0.f, 0.f, 0.f};

  const int fbase = wave * 2048 + lane * 8;

  auto stage = [&](int buf, int kt){
    const int k0 = kt * 64;
    #pragma unroll
    for (int c = 0; c < 4; ++c){
      int f = fbase + c * 512;
      int r = f >> 6, cc = f & 63;
      int ra = m0 + r; if (ra >= M) ra = M - 1;     // row clamp (only GEMM1 needs it)
      gload_lds16(A + (size_t)ra * K + k0 + cc, &As[buf][wave * 2048 + c * 512]);
    }
    #pragma unroll
    for (int c = 0; c < 4; ++c){
      int f = fbase + c * 512;
      int r = f >> 6, cc = f & 63;
      gload_lds16(B + (size_t)(n0 + r) * K + k0 + cc, &Bs[buf][wave * 2048 + c * 512]);
    }
  };

  stage(0, 0);
  __syncthreads();
  int cur = 0;
  for (int kt = 0; kt < nkt; ++kt){
    if (kt + 1 < nkt) stage(cur ^ 1, kt + 1);
    const u16* as = As[cur];
    const u16* bs = Bs[cur];
    #pragma unroll
    for (int kk = 0; kk < 2; ++kk){
      const int ko = kk * 32 + (lane >> 4) * 8;
      short8 af[4], bq[4];
      #pragma unroll
      for (int mi = 0; mi < 4; ++mi)
        af[mi] = *(const short8*)(as + (wm * 64 + mi * 16 + (lane & 15)) * 64 + ko);
      #pragma unroll
      for (int ni = 0; ni < 4; ++ni)
        bq[ni] = *(const short8*)(bs + (wn * 64 + ni * 16 + (lane & 15)) * 64 + ko);
      #pragma unroll
      for (int mi = 0; mi < 4; ++mi)
        #pragma unroll
        for (int ni = 0; ni < 4; ++ni)
          acc[mi][ni] = __builtin_amdgcn_mfma_f32_16x16x32_bf16(af[mi], bq[ni], acc[mi][ni], 0, 0, 0);
    }
    __syncthreads();
    cur ^= 1;
  }

  // epilogue: C/D layout col = lane&15, row = (lane>>4)*4 + reg  [m89-verified]
  const int rbase = m0 + wm * 64 + ((lane >> 4) << 2);
  const int cbase = n0 + wn * 64 + (lane & 15);
  #pragma unroll
  for (int mi = 0; mi < 4; ++mi){
    #pragma unroll
    for (int ni = 0; ni < 4; ++ni){
      const int col = cbase + ni * 16;
      float bv = (EPI == 2 || EPI == 3) ? bias[col] : 0.f;
      #pragma unroll
      for (int r = 0; r < 4; ++r){
        const int row = rbase + mi * 16 + r;
        if (row < M){
          float v = acc[mi][ni][r];
          if (EPI == 1)      v = fmaxf(v, 0.f);
          else if (EPI == 2) v = tanhf(v + bv);
          else if (EPI == 3) v = v + bv;
          if (OUT == 0)      ((u16*)C)[(size_t)row * ldc + col] = f2bf(v);
          else if (OUT == 1) ((float*)C)[(size_t)row * ldc + col] = v;
          else ((float*)C)[(size_t)row * 128 + (col & 127) + (size_t)(col >> 7) * ((size_t)M * 128)] = v;
        }
      }
    }
  }
}

// ---------- launch ----------
extern "C" void kernel_launch(void* const* d_in, const int* in_sizes, int n_in,
                              void* d_out, int out_size, void* d_ws, size_t ws_size,
                              hipStream_t stream){
  const float* features = (const float*)d_in[0];
  const int*   neigh1   = (const int*)  d_in[1];
  const int*   neigh2   = (const int*)  d_in[2];
  const float* eps      = (const float*)d_in[3];
  const float* W1       = (const float*)d_in[4];
  const float* W2       = (const float*)d_in[5];
  const float* W3       = (const float*)d_in[6];
  const float* Wd1      = (const float*)d_in[7];
  const float* b1       = (const float*)d_in[8];
  const float* Wd2      = (const float*)d_in[9];
  const float* b2       = (const float*)d_in[10];
  const float* M1       = (const float*)d_in[11];
  const float* M2       = (const float*)d_in[12];
  float* out = (float*)d_out;
  char*  ws  = (char*)d_ws;

  // workspace layout (bytes, all 256-aligned); aliases are safe by stream order:
  //  [0, 25.6M)         features_bf16, later reused as h1
  //  [25.6M, 51.2M)     agg1, later reused as {agg2, hB, o1, o2, tmp}
  //  [51.2M, ~52.1M)    bf16 weights
  u16* fB   = (u16*)(ws);
  u16* h1   = fB;                                    // alias: fB dead after agg1 gather
  u16* agg1 = (u16*)(ws + 25600000);
  u16* agg2 = agg1;                                  // alias: agg1 dead after GEMM1
  u16* hB   = (u16*)(ws + 29794304);
  u16* o1   = (u16*)(ws + 31891456);
  u16* o2   = (u16*)(ws + 36085760);
  u16* tmpb = (u16*)(ws + 40280064);
  u16* W1b  = (u16*)(ws + 51200000);
  u16* Wcb  = W1b  + 65536;   // [W2 rows; W3 rows] = 256x256
  u16* Wd1b = Wcb  + 65536;
  u16* Wd2b = Wd1b + 32768;
  u16* M1b  = Wd2b + 65536;
  u16* M2b  = M1b  + 65536;
  u16* Gtb  = M2b  + 65536;   // Gt = M2 @ M1^T  (so Gt^T = M1 @ M2^T = G)

  // 1) converts
  convert_f2b<<<12500, 256, 0, stream>>>(features, fB, 3200000);
  convert_weights<<<352, 256, 0, stream>>>(W1, W2, W3, Wd1, Wd2, M1, M2,
                                           W1b, Wcb, Wd1b, Wd2b, M1b, M2b);
  // 2) Gt = M2 @ M1^T   [256x256x256]
  gemm_bt<0,0><<<dim3(2,2), 256, 0, stream>>>(M2b, M1b, Gtb, 256, nullptr, 256, 256, 256);
  // 3) agg1 = mean(features[neigh1])  [50000x256] bf16
  gather_mean<<<25000, 256, 0, stream>>>((const u32*)fB, neigh1, (u32*)agg1, 50000);
  // 4) h1 = relu(agg1 @ W1^T)  [50000x256] bf16
  gemm_bt<1,0><<<dim3(391,2), 256, 0, stream>>>(agg1, W1b, h1, 256, nullptr, 50000, 256, 256);
  // 5) agg2 = mean(h1[neigh2])  [8192x256] bf16
  gather_mean<<<4096, 256, 0, stream>>>((const u32*)h1, neigh2, (u32*)agg2, 8192);
  // 6) [mu | logvar] = relu(agg2 @ [W2;W3]^T) -> d_out (split f32)
  gemm_bt<1,2><<<dim3(64,2), 256, 0, stream>>>(agg2, Wcb, out, 0, nullptr, 8192, 256, 256);
  // 7) h = eps*exp(logvar) + mu  [8192x128] bf16
  reparam<<<2048, 256, 0, stream>>>(out, out + 1048576, eps, (u32*)hB, 524288);
  // 8) o1 = tanh(h @ Wd1^T + b1)  [8192x256] bf16   (K=128)
  gemm_bt<2,0><<<dim3(64,2), 256, 0, stream>>>(hB, Wd1b, o1, 256, b1, 8192, 256, 128);
  // 9) o2 = o1 @ Wd2^T + b2  [8192x256] bf16
  gemm_bt<3,0><<<dim3(64,2), 256, 0, stream>>>(o1, Wd2b, o2, 256, b2, 8192, 256, 256);
  // 10) tmp = o2 @ Gt^T = o2 @ M1 @ M2^T  [8192x256] bf16
  gemm_bt<0,0><<<dim3(64,2), 256, 0, stream>>>(o2, Gtb, tmpb, 256, nullptr, 8192, 256, 256);
  // 11) adj = tmp @ o2^T  [8192x8192] f32 -> d_out + 2*8192*128
  gemm_bt<0,1><<<dim3(64,64), 256, 0, stream>>>(tmpb, o2, out + 2097152, 8192, nullptr, 8192, 8192, 256);
}